// Round 17
// baseline (4717.503 us; speedup 1.0000x reference)
//
#include <hip/hip_runtime.h>
#include <cstdint>

typedef __bf16 bf16x8 __attribute__((ext_vector_type(8)));
typedef float  f32x4  __attribute__((ext_vector_type(4)));

union U4B { uint4 u; bf16x8 b; };
__device__ __forceinline__ bf16x8 as_bf(uint4 u) { U4B x; x.u = u; return x.b; }

// float -> bf16 bits, round-to-nearest-even (finite inputs)
__device__ __forceinline__ unsigned short f2b(float x) {
  unsigned int u = __float_as_uint(x);
  unsigned int r = (u + 0x7fffu + ((u >> 16) & 1u)) >> 16;
  return (unsigned short)r;
}
__device__ __forceinline__ float b2f(unsigned int bits_lo16) {
  return __uint_as_float(bits_lo16 << 16);
}

__device__ __forceinline__ float sigm(float x) {
  float e = __builtin_amdgcn_exp2f(x * -1.4426950408889634f);
  return __builtin_amdgcn_rcpf(1.0f + e);
}
__device__ __forceinline__ float tanh_fast(float x) {
  float e = __builtin_amdgcn_exp2f(x * 2.8853900817779268f);
  return 1.0f - 2.0f * __builtin_amdgcn_rcpf(e + 1.0f);
}

// ---------------- prep: build permuted bf16 weight layouts in ws ----------------
// recT [1024 col'][256 k]   : col' = 4u+g  <-> orig col = u + 256g
// kb2  [128 ch][1024 col']  : (kernel + bias) same permutation
// dwT  [128 class][256 k]   : dense_w transposed
__global__ void prep_kernel(const float* __restrict__ rec,
                            const float* __restrict__ kern,
                            const float* __restrict__ bias,
                            const float* __restrict__ dw,
                            unsigned short* __restrict__ recT,
                            unsigned short* __restrict__ kb2,
                            unsigned short* __restrict__ dwT) {
  int id = blockIdx.x * 256 + threadIdx.x;
  if (id < 262144) {                       // 1024*256
    int colp = id >> 8, k = id & 255;
    int u = colp >> 2, g = colp & 3;
    recT[colp * 256 + k] = f2b(rec[k * 1024 + u + 256 * g]);
  } else if (id < 262144 + 131072) {       // 128*1024
    int i = id - 262144;
    int ch = i >> 10, colp = i & 1023;
    int u = colp >> 2, g = colp & 3;
    int oc = u + 256 * g;
    kb2[ch * 1024 + colp] = f2b(kern[ch * 1024 + oc] + bias[oc]);
  } else {                                 // 128*256
    int i = id - 262144 - 131072;
    int cls = i >> 8, k = i & 255;
    dwT[cls * 256 + k] = f2b(dw[k * 128 + cls]);
  }
}

// ---------------- main persistent LSTM kernel ----------------
// LATENCY-HIDING rebalance of R9 (the 5-round-validated best):
// 64 blocks x 1024 threads = 16 waves, amdgpu_waves_per_eu(4,4) -> exactly
// 4 waves/SIMD at 128 regs/wave (R12/R13/R16 showed the step is
// latency-serialized at 2 waves/SIMD: ~600 instr take ~5000 cyc, and the
// ~3.4us/step VMEM add-on is byte-count- and pattern-insensitive).
// Wave wid owns gate-cols' [wid*64, wid*64+64) = 4 m-tiles:
//   m0 : AGPR-resident (32 accum regs, pinned)
//   m1 : LDS-resident  (16 waves x 8 KB = 128 KB)
//   m2,3 : streamed from L2, window-2 rotation (2|8 phase-aligned)
// Per-CU stream halves vs R9 (64 KB/step); wave parallelism doubles.
// Math identical to R9 (same per-unit k-order) -> absmax unchanged.
__global__ __launch_bounds__(1024)
__attribute__((amdgpu_waves_per_eu(4, 4)))
void lstm_kernel(
    const unsigned short* __restrict__ recT,
    const unsigned short* __restrict__ kb2,
    const unsigned short* __restrict__ dwT,
    const int* __restrict__ x,
    const float* __restrict__ dense_b,
    float* __restrict__ out) {
  __shared__ uint4 A_lds[16][8][64];            // 128 KB (m1): [wid][k][lane]
  __shared__ unsigned short h_buf[2][16][264];  // 16.9 KB (R9 layout)

  const int tid   = threadIdx.x;
  const int lane  = tid & 63;
  const int wid   = tid >> 6;      // 0..15
  const int row16 = lane & 15;     // batch row within tile
  const int kg    = lane >> 4;     // 0..3
  const int rbase = blockIdx.x << 4;

  const unsigned short* recBase = recT + ((wid * 64 + row16) * 256 + kg * 8);

  // m0 into AGPRs (32 accum regs), loaded once
  uint4 af[8];
#pragma unroll
  for (int k = 0; k < 8; ++k) {
    af[k] = *(const uint4*)(recBase + k * 32);
    asm volatile("" : "+a"(af[k].x), "+a"(af[k].y), "+a"(af[k].z), "+a"(af[k].w));
  }

  // m1 into LDS (per-wave-private plane), staged once
#pragma unroll
  for (int k = 0; k < 8; ++k)
    A_lds[wid][k][lane] = *(const uint4*)(recBase + 4096 + k * 32);

  // m2,3 stream bases; window-2 (slot = k&1), preload frags 0,1
  const unsigned short* sb2 = recBase + 2 * 4096;
  const unsigned short* sb3 = recBase + 3 * 4096;
  uint4 st2[2], st3[2];
#pragma unroll
  for (int k = 0; k < 2; ++k) {
    st2[k] = *(const uint4*)(sb2 + k * 32);
    st3[k] = *(const uint4*)(sb3 + k * 32);
  }

  // zero h(0)
  for (int e = tid; e < 16 * 264; e += 1024) (&h_buf[0][0][0])[e] = 0;

  float c_state[4];
#pragma unroll
  for (int m = 0; m < 4; ++m) c_state[m] = 0.0f;

  const int* xrow = x + (rbase + row16) * 512;
  int idx_cur = xrow[0];
  const int colb = wid * 64;

  // preload kq for t=0 (4 gate-quads per lane)
  uint2 kq[4];
  {
    const unsigned short* kb = kb2 + (idx_cur * 1024 + colb + kg * 4);
#pragma unroll
    for (int m = 0; m < 4; ++m) kq[m] = *(const uint2*)(kb + m * 16);
  }

  __syncthreads();

  int cur = 0;

#pragma unroll 1
  for (int t = 0; t < 512; ++t) {
    unsigned z6 = 0, zL = 0;
    asm volatile("" : "+v"(z6), "+v"(zL));
    const unsigned short* sb2v = sb2 + z6;
    const unsigned short* sb3v = sb3 + z6;
    const unsigned loff = lane * 16 + zL;

    int idx_next = xrow[(t + 1 < 512) ? t + 1 : 511];

    const unsigned short* hrow = &h_buf[cur][row16][0];
    unsigned short* hn = &h_buf[cur ^ 1][row16][wid * 16 + kg];

    // GEMM: m0 (AGPR) + m1 (LDS) + m2,3 (streamed)
    f32x4 a0 = {0,0,0,0}, a1 = {0,0,0,0}, a2 = {0,0,0,0}, a3 = {0,0,0,0};
#pragma unroll
    for (int k = 0; k < 8; ++k) {
      uint4 hf = *(const uint4*)(hrow + k * 32 + kg * 8);
      a0 = __builtin_amdgcn_mfma_f32_16x16x32_bf16(as_bf(af[k]), as_bf(hf), a0, 0, 0, 0);
      uint4 t1 = *(const uint4*)((const char*)A_lds + (wid * 8 + k) * 1024 + loff);
      a1 = __builtin_amdgcn_mfma_f32_16x16x32_bf16(as_bf(t1), as_bf(hf), a1, 0, 0, 0);
      a2 = __builtin_amdgcn_mfma_f32_16x16x32_bf16(as_bf(st2[k & 1]), as_bf(hf), a2, 0, 0, 0);
      a3 = __builtin_amdgcn_mfma_f32_16x16x32_bf16(as_bf(st3[k & 1]), as_bf(hf), a3, 0, 0, 0);
      const int kp = (k + 2) & 7;   // window-2 prefetch (A time-invariant)
      st2[k & 1] = *(const uint4*)(sb2v + kp * 32);
      st3[k & 1] = *(const uint4*)(sb3v + kp * 32);
    }

    // gates (consume kq), fully in-register
    {
      f32x4 ag[4] = {a0, a1, a2, a3};
#pragma unroll
      for (int m = 0; m < 4; ++m) {
        float zi = ag[m][0] + b2f(kq[m].x & 0xffffu);
        float zf = ag[m][1] + b2f(kq[m].x >> 16);
        float zg = ag[m][2] + b2f(kq[m].y & 0xffffu);
        float zo = ag[m][3] + b2f(kq[m].y >> 16);
        float c  = sigm(zf) * c_state[m] + sigm(zi) * tanh_fast(zg);
        c_state[m] = c;
        hn[m * 4] = f2b(sigm(zo) * tanh_fast(c));
      }
    }

    // rotate kq for t+1 (in flight across the barrier)
    {
      const unsigned short* kbn = kb2 + (idx_next * 1024 + colb + kg * 4);
#pragma unroll
      for (int m = 0; m < 4; ++m) kq[m] = *(const uint2*)(kbn + m * 16);
    }

    __syncthreads();
    cur ^= 1;
    idx_cur = idx_next;
  }

  // ---- final dense (MFMA) + softmax; final h is in h_buf[0] (512 even) ----
  float (*l_lds)[132] = (float (*)[132])A_lds;  // overlay logits onto A_lds
  if (wid < 8) {
    const unsigned short* dwBase = dwT + ((wid * 16 + row16) * 256 + kg * 8);
    f32x4 la = {0.f, 0.f, 0.f, 0.f};
#pragma unroll
    for (int k = 0; k < 8; ++k) {
      uint4 hf  = *(const uint4*)&h_buf[0][row16][k * 32 + kg * 8];
      uint4 afd = *(const uint4*)(dwBase + k * 32);
      la = __builtin_amdgcn_mfma_f32_16x16x32_bf16(as_bf(afd), as_bf(hf), la, 0, 0, 0);
    }
#pragma unroll
    for (int r = 0; r < 4; ++r) {
      int cls = wid * 16 + kg * 4 + r;
      l_lds[row16][cls] = la[r] + dense_b[cls];
    }
  }
  __syncthreads();

  if (tid < 512) {
    int r = tid >> 5, cg = tid & 31;   // 16 rows x 32 col-groups of 4
    float4 v = *(const float4*)&l_lds[r][cg * 4];
    float mx = fmaxf(fmaxf(v.x, v.y), fmaxf(v.z, v.w));
#pragma unroll
    for (int sh = 1; sh < 32; sh <<= 1) mx = fmaxf(mx, __shfl_xor(mx, sh));
    const float L2E = 1.4426950408889634f;
    float e0 = __builtin_amdgcn_exp2f((v.x - mx) * L2E);
    float e1 = __builtin_amdgcn_exp2f((v.y - mx) * L2E);
    float e2 = __builtin_amdgcn_exp2f((v.z - mx) * L2E);
    float e3 = __builtin_amdgcn_exp2f((v.w - mx) * L2E);
    float sm = e0 + e1 + e2 + e3;
#pragma unroll
    for (int sh = 1; sh < 32; sh <<= 1) sm += __shfl_xor(sm, sh);
    float inv = __builtin_amdgcn_rcpf(sm);
    float4 o = {e0 * inv, e1 * inv, e2 * inv, e3 * inv};
    *(float4*)&out[(rbase + r) * 128 + cg * 4] = o;
  }
}

extern "C" void kernel_launch(void* const* d_in, const int* in_sizes, int n_in,
                              void* d_out, int out_size, void* d_ws, size_t ws_size,
                              hipStream_t stream) {
  const int*   x      = (const int*)d_in[0];    // [1024][512] int32
  const float* kern   = (const float*)d_in[1];  // [128][1024]
  const float* rec    = (const float*)d_in[2];  // [256][1024]
  const float* bias   = (const float*)d_in[3];  // [1024]
  const float* dw     = (const float*)d_in[4];  // [256][128]
  const float* db     = (const float*)d_in[5];  // [128]
  float* outp = (float*)d_out;                  // [1024][128]

  unsigned char* ws = (unsigned char*)d_ws;
  unsigned short* recT = (unsigned short*)(ws);            // 512 KB
  unsigned short* kb2  = (unsigned short*)(ws + 524288);   // 256 KB
  unsigned short* dwT  = (unsigned short*)(ws + 786432);   //  64 KB

  prep_kernel<<<1664, 256, 0, stream>>>(rec, kern, bias, dw, recT, kb2, dwT);
  lstm_kernel<<<64, 1024, 0, stream>>>(recT, kb2, dwT, x, db, outp);
}